// Round 1
// baseline (594.183 us; speedup 1.0000x reference)
//
#include <hip/hip_runtime.h>
#include <hip/hip_bf16.h>

// Problem constants (reference: BS=32, N=512)
#define BSZ 32
#define NN  512

// Output flat offsets (elements, f32), in reference return order:
//  X_cat [32,512,32]       = 524288
//  C_cat [32,512,6]        =  98304
//  E1    [32,512,512,5]    = 41943040
//  E2    [32,512,512,5]    = 41943040
//  BD1   [32,512,512,3]    = 25165824
static const long O_XC = 0;
static const long O_CC = 524288L;
static const long O_E1 = 622592L;
static const long O_E2 = 42565632L;
static const long O_BD = 84508672L;

typedef float f32x4 __attribute__((ext_vector_type(4)));

// ---------------------------------------------------------------------------
// Kernel A: per-sample alignment map (unchanged — trivial cost).
// p2m[i*N+j] = product position aligned to reactant j, or -1 if unmapped.
// ---------------------------------------------------------------------------
__global__ __launch_bounds__(NN) void align_kernel(
    const int* __restrict__ amn, const int* __restrict__ ma,
    int* __restrict__ p2m)
{
    const int i = blockIdx.x;
    const int t = threadIdx.x;          // 0..511

    __shared__ int red[NN];
    __shared__ int table[NN + 1];

    const int a = ma[i * NN + t];
    red[t] = a;
    __syncthreads();
    for (int s = NN / 2; s > 0; s >>= 1) {
        if (t < s) red[t] = max(red[t], red[t + s]);
        __syncthreads();
    }
    const int prod_assign = red[0];

    table[t] = -1;
    if (t == 0) table[NN] = -1;
    __syncthreads();

    const int m = amn[i * NN + t];
    if (a == prod_assign && m > 0 && m <= NN) table[m] = t;
    __syncthreads();

    int p = -1;
    if (a < prod_assign && m > 0 && m <= NN) p = table[m];
    p2m[i * NN + t] = p;
}

// ---------------------------------------------------------------------------
// Kernel B: node features, float4-vectorized X path. One thread per (i,j).
// (unchanged — ~2.6 MB of traffic, negligible)
// ---------------------------------------------------------------------------
__global__ __launch_bounds__(256) void node_kernel(
    const float* __restrict__ X,
    const float* __restrict__ AC,
    const int* __restrict__ p2m,
    float* __restrict__ out)
{
    const int idx = blockIdx.x * 256 + threadIdx.x;
    if (idx >= BSZ * NN) return;
    const int i = idx >> 9;
    const int p = p2m[idx];

    const float4* xr4 = (const float4*)(X + (size_t)idx * 16);
    float4* ox4 = (float4*)(out + O_XC + (size_t)idx * 32);
#pragma unroll
    for (int c = 0; c < 4; ++c) ox4[c] = xr4[c];
    if (p >= 0) {
        const float4* xp4 = (const float4*)(X + ((size_t)i * NN + p) * 16);
#pragma unroll
        for (int c = 0; c < 4; ++c) ox4[4 + c] = xp4[c];
    } else {
        const float4 z = make_float4(0.f, 0.f, 0.f, 0.f);
#pragma unroll
        for (int c = 0; c < 4; ++c) ox4[4 + c] = z;
    }

    const float* cr = AC + (size_t)idx * 3;
    float* oc = out + O_CC + (size_t)idx * 6;
#pragma unroll
    for (int c = 0; c < 3; ++c) oc[c] = cr[c];
    if (p >= 0) {
        const float* cp = AC + ((size_t)i * NN + p) * 3;
#pragma unroll
        for (int c = 0; c < 3; ++c) oc[3 + c] = cp[c];
    } else {
#pragma unroll
        for (int c = 0; c < 3; ++c) oc[3 + c] = 0.0f;
    }
}

// ---------------------------------------------------------------------------
// Kernel C v2: edge features, LDS-staged gather. One block per (i,j1) row.
//
// Change vs v1: the per-element global gathers Erow[p2*5+c] / Brow[p2*3+c]
// were fully divergent wave loads (64 lanes -> ~60 distinct cachelines per
// instruction, serialized in the TA/L1 pipe). Now each mapped block first
// stages its 10 KB E-row + 6 KB BD-row into LDS with coalesced float4 loads
// (each product row is gathered exactly once per sample -> reads stay at the
// 170 MB minimum), then gathers from LDS (random-bank ds_read, ~6-10 cyc per
// wave instr). Unmapped rows (p1 < 0, half the blocks) take a pure
// constant-fill path. All big streaming stores are nontemporal so the 437 MB
// write stream doesn't evict the E-row read stream from L2.
// ---------------------------------------------------------------------------
__global__ __launch_bounds__(NN) void edge_kernel(
    const float* __restrict__ E,
    const float* __restrict__ BD,
    const int* __restrict__ p2m,
    float* __restrict__ out)
{
    const int b  = blockIdx.x;          // i*N + j1
    const int i  = b >> 9;
    const int j1 = b & (NN - 1);
    const int t  = threadIdx.x;

    f32x4* oE1 = (f32x4*)(out + O_E1 + (size_t)b * (NN * 5));
    f32x4* oE2 = (f32x4*)(out + O_E2 + (size_t)b * (NN * 5));
    f32x4* oBD = (f32x4*)(out + O_BD + (size_t)b * (NN * 3));

    __shared__ int   sp[NN];
    __shared__ float sE[NN * 5];        // 10240 B, gathered-source E row (product order)
    __shared__ float sB[NN * 3];        //  6144 B, gathered-source BD row

    // p1 is block-uniform; read it directly (no need for the full sp[] yet).
    const int p1 = p2m[i * NN + j1];

    if (p1 < 0) {
        // Unmapped row: E1 = 0, E2 = onehot0 everywhere, BD = 0. Pure fill.
        const f32x4 z = {0.f, 0.f, 0.f, 0.f};
        for (int f = t; f < 640; f += NN) {
            f32x4 v2;
#pragma unroll
            for (int k = 0; k < 4; ++k) {
                const int g  = 4 * f + k;
                const int j2 = g / 5;
                const int c  = g - j2 * 5;
                v2[k] = (c == 0) ? 1.0f : 0.0f;
            }
            __builtin_nontemporal_store(z,  oE1 + f);
            __builtin_nontemporal_store(v2, oE2 + f);
        }
        for (int f = t; f < 384; f += NN)
            __builtin_nontemporal_store(z, oBD + f);
        return;
    }

    // Mapped row: stage sp + the gathered product row into LDS, coalesced.
    sp[t] = p2m[i * NN + t];
    {
        const f32x4* Er4 = (const f32x4*)(E  + ((size_t)i * NN + p1) * (NN * 5));
        const f32x4* Br4 = (const f32x4*)(BD + ((size_t)i * NN + p1) * (NN * 3));
        f32x4* sE4 = (f32x4*)sE;
        f32x4* sB4 = (f32x4*)sB;
        sE4[t] = Er4[t];
        if (t < 128) sE4[NN + t] = Er4[NN + t];
        if (t < 384) sB4[t] = Br4[t];
    }
    __syncthreads();

    // E1 + E2 fused: one pass over the 640 output float4s of each region.
    for (int f = t; f < 640; f += NN) {
        f32x4 v1, v2;
#pragma unroll
        for (int k = 0; k < 4; ++k) {
            const int g   = 4 * f + k;
            const int j2  = g / 5;          // compiler magic-mul
            const int c   = g - j2 * 5;
            const int p2  = sp[j2];
            const int p2c = p2 < 0 ? 0 : p2;
            const float e = sE[p2c * 5 + c];   // LDS gather (masked below)
            const bool pair = (p2 >= 0);
            v1[k] = pair ? e : 0.0f;
            v2[k] = pair ? 0.0f : (c == 0 ? 1.0f : 0.0f);
        }
        __builtin_nontemporal_store(v1, oE1 + f);
        __builtin_nontemporal_store(v2, oE2 + f);
    }

    // BD1
    for (int f = t; f < 384; f += NN) {
        f32x4 v;
#pragma unroll
        for (int k = 0; k < 4; ++k) {
            const int g   = 4 * f + k;
            const int j2  = g / 3;
            const int c   = g - j2 * 3;
            const int p2  = sp[j2];
            const int p2c = p2 < 0 ? 0 : p2;
            const float x = sB[p2c * 3 + c];
            v[k] = (p2 >= 0) ? x : 0.0f;
        }
        __builtin_nontemporal_store(v, oBD + f);
    }
}

extern "C" void kernel_launch(void* const* d_in, const int* in_sizes, int n_in,
                              void* d_out, int out_size, void* d_ws, size_t ws_size,
                              hipStream_t stream) {
    const float* X  = (const float*)d_in[0];
    const float* E  = (const float*)d_in[1];
    const float* AC = (const float*)d_in[2];
    const float* BD = (const float*)d_in[3];
    const int* amn = (const int*)d_in[4];
    const int* ma  = (const int*)d_in[5];
    float* out = (float*)d_out;

    int* p2m = (int*)d_ws;   // 32*512 ints = 64 KB

    align_kernel<<<BSZ, NN, 0, stream>>>(amn, ma, p2m);
    node_kernel<<<(BSZ * NN + 255) / 256, 256, 0, stream>>>(X, AC, p2m, out);
    edge_kernel<<<BSZ * NN, NN, 0, stream>>>(E, BD, p2m, out);
}

// Round 2
// 587.981 us; speedup vs baseline: 1.0105x; 1.0105x over previous
//
#include <hip/hip_runtime.h>
#include <hip/hip_bf16.h>

// Problem constants (reference: BS=32, N=512)
#define BSZ 32
#define NN  512

// Output flat offsets (elements, f32), in reference return order:
//  X_cat [32,512,32]       = 524288
//  C_cat [32,512,6]        =  98304
//  E1    [32,512,512,5]    = 41943040
//  E2    [32,512,512,5]    = 41943040
//  BD1   [32,512,512,3]    = 25165824
static const long O_XC = 0;
static const long O_CC = 524288L;
static const long O_E1 = 622592L;
static const long O_E2 = 42565632L;
static const long O_BD = 84508672L;

typedef float f32x4 __attribute__((ext_vector_type(4)));

// ---------------------------------------------------------------------------
// Kernel A: per-sample alignment map (unchanged — trivial cost).
// p2m[i*N+j] = product position aligned to reactant j, or -1 if unmapped.
// ---------------------------------------------------------------------------
__global__ __launch_bounds__(NN) void align_kernel(
    const int* __restrict__ amn, const int* __restrict__ ma,
    int* __restrict__ p2m)
{
    const int i = blockIdx.x;
    const int t = threadIdx.x;          // 0..511

    __shared__ int red[NN];
    __shared__ int table[NN + 1];

    const int a = ma[i * NN + t];
    red[t] = a;
    __syncthreads();
    for (int s = NN / 2; s > 0; s >>= 1) {
        if (t < s) red[t] = max(red[t], red[t + s]);
        __syncthreads();
    }
    const int prod_assign = red[0];

    table[t] = -1;
    if (t == 0) table[NN] = -1;
    __syncthreads();

    const int m = amn[i * NN + t];
    if (a == prod_assign && m > 0 && m <= NN) table[m] = t;
    __syncthreads();

    int p = -1;
    if (a < prod_assign && m > 0 && m <= NN) p = table[m];
    p2m[i * NN + t] = p;
}

// ---------------------------------------------------------------------------
// Kernel B: node features, float4-vectorized X path. One thread per (i,j).
// (unchanged — ~2.6 MB of traffic, negligible)
// ---------------------------------------------------------------------------
__global__ __launch_bounds__(256) void node_kernel(
    const float* __restrict__ X,
    const float* __restrict__ AC,
    const int* __restrict__ p2m,
    float* __restrict__ out)
{
    const int idx = blockIdx.x * 256 + threadIdx.x;
    if (idx >= BSZ * NN) return;
    const int i = idx >> 9;
    const int p = p2m[idx];

    const float4* xr4 = (const float4*)(X + (size_t)idx * 16);
    float4* ox4 = (float4*)(out + O_XC + (size_t)idx * 32);
#pragma unroll
    for (int c = 0; c < 4; ++c) ox4[c] = xr4[c];
    if (p >= 0) {
        const float4* xp4 = (const float4*)(X + ((size_t)i * NN + p) * 16);
#pragma unroll
        for (int c = 0; c < 4; ++c) ox4[4 + c] = xp4[c];
    } else {
        const float4 z = make_float4(0.f, 0.f, 0.f, 0.f);
#pragma unroll
        for (int c = 0; c < 4; ++c) ox4[4 + c] = z;
    }

    const float* cr = AC + (size_t)idx * 3;
    float* oc = out + O_CC + (size_t)idx * 6;
#pragma unroll
    for (int c = 0; c < 3; ++c) oc[c] = cr[c];
    if (p >= 0) {
        const float* cp = AC + ((size_t)i * NN + p) * 3;
#pragma unroll
        for (int c = 0; c < 3; ++c) oc[3 + c] = cp[c];
    } else {
#pragma unroll
        for (int c = 0; c < 3; ++c) oc[3 + c] = 0.0f;
    }
}

// ---------------------------------------------------------------------------
// Edge passes, one kernel per output region. Rationale (round 2): fused
// kernel drove 3 interleaved write streams per block (E1/E2/BD windows
// 40-170MB apart) + a read stream -> ~4k concurrent HBM streams, suspected
// DRAM page thrash (effective ~2 TB/s vs 6.2 TB/s the rocclr fill proves).
// Per-region passes give each kernel ONE sequential write window.
// 256-thread blocks -> 8 blocks/CU residency. Plain stores (nt reverted).
// ---------------------------------------------------------------------------

// E1: gathered product edges, masked. One block per (i,j1) row = 640 f32x4.
__global__ __launch_bounds__(256) void e1_kernel(
    const float* __restrict__ E,
    const int* __restrict__ p2m,
    float* __restrict__ out)
{
    const int b = blockIdx.x;           // i*N + j1
    const int i = b >> 9;
    const int t = threadIdx.x;

    f32x4* o = (f32x4*)(out + O_E1 + (size_t)b * (NN * 5));
    const int p1 = p2m[b];

    if (p1 < 0) {                       // unmapped row: all zeros
        const f32x4 z = {0.f, 0.f, 0.f, 0.f};
        for (int f = t; f < 640; f += 256) o[f] = z;
        return;
    }

    __shared__ int   sp[NN];
    __shared__ float sE[NN * 5];        // 10 KB gathered-source row
    sp[t]       = p2m[i * NN + t];
    sp[t + 256] = p2m[i * NN + t + 256];
    {
        const f32x4* Er4 = (const f32x4*)(E + ((size_t)i * NN + p1) * (NN * 5));
        f32x4* sE4 = (f32x4*)sE;
        for (int f = t; f < 640; f += 256) sE4[f] = Er4[f];
    }
    __syncthreads();

    for (int f = t; f < 640; f += 256) {
        f32x4 v;
#pragma unroll
        for (int k = 0; k < 4; ++k) {
            const int g   = 4 * f + k;
            const int j2  = g / 5;      // compiler magic-mul
            const int c   = g - j2 * 5;
            const int p2  = sp[j2];
            const int p2c = p2 < 0 ? 0 : p2;
            const float e = sE[p2c * 5 + c];
            v[k] = (p2 >= 0) ? e : 0.0f;
        }
        o[f] = v;
    }
}

// E2: (1-pair)*onehot0 — pure pattern fill, zero input reads.
// Serves as the in-kernel control comparable to __amd_rocclr_fillBuffer.
__global__ __launch_bounds__(256) void e2_kernel(
    const int* __restrict__ p2m,
    float* __restrict__ out)
{
    const int b = blockIdx.x;
    const int i = b >> 9;
    const int t = threadIdx.x;

    f32x4* o = (f32x4*)(out + O_E2 + (size_t)b * (NN * 5));
    const int p1 = p2m[b];

    if (p1 < 0) {                       // unmapped row: onehot0 everywhere
        for (int f = t; f < 640; f += 256) {
            f32x4 v;
#pragma unroll
            for (int k = 0; k < 4; ++k) {
                const int g  = 4 * f + k;
                const int j2 = g / 5;
                const int c  = g - j2 * 5;
                v[k] = (c == 0) ? 1.0f : 0.0f;
            }
            o[f] = v;
        }
        return;
    }

    __shared__ int sp[NN];
    sp[t]       = p2m[i * NN + t];
    sp[t + 256] = p2m[i * NN + t + 256];
    __syncthreads();

    for (int f = t; f < 640; f += 256) {
        f32x4 v;
#pragma unroll
        for (int k = 0; k < 4; ++k) {
            const int g  = 4 * f + k;
            const int j2 = g / 5;
            const int c  = g - j2 * 5;
            v[k] = (sp[j2] >= 0) ? 0.0f : (c == 0 ? 1.0f : 0.0f);
        }
        o[f] = v;
    }
}

// BD1: gathered bond dirs, masked. One block per row = 384 f32x4.
__global__ __launch_bounds__(256) void bd_kernel(
    const float* __restrict__ BD,
    const int* __restrict__ p2m,
    float* __restrict__ out)
{
    const int b = blockIdx.x;
    const int i = b >> 9;
    const int t = threadIdx.x;

    f32x4* o = (f32x4*)(out + O_BD + (size_t)b * (NN * 3));
    const int p1 = p2m[b];

    if (p1 < 0) {
        const f32x4 z = {0.f, 0.f, 0.f, 0.f};
        for (int f = t; f < 384; f += 256) o[f] = z;
        return;
    }

    __shared__ int   sp[NN];
    __shared__ float sB[NN * 3];        // 6 KB gathered-source row
    sp[t]       = p2m[i * NN + t];
    sp[t + 256] = p2m[i * NN + t + 256];
    {
        const f32x4* Br4 = (const f32x4*)(BD + ((size_t)i * NN + p1) * (NN * 3));
        f32x4* sB4 = (f32x4*)sB;
        for (int f = t; f < 384; f += 256) sB4[f] = Br4[f];
    }
    __syncthreads();

    for (int f = t; f < 384; f += 256) {
        f32x4 v;
#pragma unroll
        for (int k = 0; k < 4; ++k) {
            const int g   = 4 * f + k;
            const int j2  = g / 3;
            const int c   = g - j2 * 3;
            const int p2  = sp[j2];
            const int p2c = p2 < 0 ? 0 : p2;
            const float x = sB[p2c * 3 + c];
            v[k] = (p2 >= 0) ? x : 0.0f;
        }
        o[f] = v;
    }
}

extern "C" void kernel_launch(void* const* d_in, const int* in_sizes, int n_in,
                              void* d_out, int out_size, void* d_ws, size_t ws_size,
                              hipStream_t stream) {
    const float* X  = (const float*)d_in[0];
    const float* E  = (const float*)d_in[1];
    const float* AC = (const float*)d_in[2];
    const float* BD = (const float*)d_in[3];
    const int* amn = (const int*)d_in[4];
    const int* ma  = (const int*)d_in[5];
    float* out = (float*)d_out;

    int* p2m = (int*)d_ws;   // 32*512 ints = 64 KB

    align_kernel<<<BSZ, NN, 0, stream>>>(amn, ma, p2m);
    node_kernel<<<(BSZ * NN + 255) / 256, 256, 0, stream>>>(X, AC, p2m, out);
    e1_kernel<<<BSZ * NN, 256, 0, stream>>>(E, p2m, out);
    e2_kernel<<<BSZ * NN, 256, 0, stream>>>(p2m, out);
    bd_kernel<<<BSZ * NN, 256, 0, stream>>>(BD, p2m, out);
}